// Round 2
// baseline (5687.719 us; speedup 1.0000x reference)
//
#include <hip/hip_runtime.h>
#include <stdint.h>
#include <math.h>

// Problem constants (from reference)
constexpr int kB = 8;      // clouds
constexpr int kP = 8192;   // points per cloud
constexpr int kF = 32;     // feature dim
constexpr int kM = 2048;   // centroids per cloud (P * 0.25)
constexpr int kK = 64;     // max neighbors
constexpr int kH = 64;     // hidden dim
constexpr int kO = 128;    // output dim

// Exact-f32 squared distance matching numpy: square elementwise, then
// sequential sum ((dx2+dy2)+dz2). contract(off) forbids fma fusion so this
// matches numpy bit-for-bit regardless of -ffp-contract=fast default.
__device__ __forceinline__ float dist2(float ax, float ay, float az,
                                       float bx, float by, float bz) {
#pragma clang fp contract(off)
    float dx = ax - bx, dy = ay - by, dz = az - bz;
    return (dx * dx + dy * dy) + dz * dz;
}

// ---------------------------------------------------------------------------
// Kernel 1: farthest point sampling. One block (1024 threads) per cloud.
// Each thread owns 8 points in registers (pos + running min-dist).
// Argmax via packed monotonic key: (float_bits(d) << 32) | ~idx.
// Non-negative IEEE floats are bit-monotonic, so u64 max = max value with
// lowest-index tie-break (numpy argmax first-occurrence semantics).
// Winner's coordinates carried alongside the key through the reduction.
// ---------------------------------------------------------------------------
__global__ __launch_bounds__(1024) void fps_kernel(const float* __restrict__ pos,
                                                   float* __restrict__ cent_out) {
    const int b = blockIdx.x;
    const int tid = threadIdx.x;
    const float* pb = pos + (size_t)b * kP * 3;

    float px[8], py[8], pz[8], dd[8];
#pragma unroll
    for (int q = 0; q < 8; ++q) {
        int i = tid + q * 1024;
        px[q] = pb[i * 3 + 0];
        py[q] = pb[i * 3 + 1];
        pz[q] = pb[i * 3 + 2];
        dd[q] = INFINITY;
    }

    __shared__ float s_lx, s_ly, s_lz;
    __shared__ unsigned long long wkey[16];
    __shared__ float wx[16], wy[16], wz[16];

    if (tid == 0) {
        // first selected index is 0 (owned by tid 0, q 0)
        s_lx = px[0]; s_ly = py[0]; s_lz = pz[0];
        cent_out[(size_t)(b * kM) * 3 + 0] = px[0];
        cent_out[(size_t)(b * kM) * 3 + 1] = py[0];
        cent_out[(size_t)(b * kM) * 3 + 2] = pz[0];
    }
    __syncthreads();
    float lx = s_lx, ly = s_ly, lz = s_lz;

    const int wave = tid >> 6, lane = tid & 63;

    for (int m = 1; m < kM; ++m) {
        unsigned long long bk = 0ull;
        float bx = 0.f, by = 0.f, bz = 0.f;
#pragma unroll
        for (int q = 0; q < 8; ++q) {
            float d2 = dist2(px[q], py[q], pz[q], lx, ly, lz);
            float nd = fminf(dd[q], d2);
            dd[q] = nd;
            unsigned int idx = (unsigned int)(tid + q * 1024);
            unsigned long long key =
                ((unsigned long long)__float_as_uint(nd) << 32) | (unsigned int)(~idx);
            if (key > bk) { bk = key; bx = px[q]; by = py[q]; bz = pz[q]; }
        }
        // wave-level u64-max reduce, coords carried along
#pragma unroll
        for (int off = 32; off >= 1; off >>= 1) {
            unsigned long long ok = __shfl_down(bk, off, 64);
            float ox = __shfl_down(bx, off, 64);
            float oy = __shfl_down(by, off, 64);
            float oz = __shfl_down(bz, off, 64);
            if (ok > bk) { bk = ok; bx = ox; by = oy; bz = oz; }
        }
        if (lane == 0) { wkey[wave] = bk; wx[wave] = bx; wy[wave] = by; wz[wave] = bz; }
        __syncthreads();
        if (tid == 0) {
            unsigned long long k = wkey[0];
            float X = wx[0], Y = wy[0], Z = wz[0];
#pragma unroll
            for (int w = 1; w < 16; ++w) {
                if (wkey[w] > k) { k = wkey[w]; X = wx[w]; Y = wy[w]; Z = wz[w]; }
            }
            size_t o = (size_t)(b * kM + m) * 3;
            cent_out[o + 0] = X;
            cent_out[o + 1] = Y;
            cent_out[o + 2] = Z;
            s_lx = X; s_ly = Y; s_lz = Z;
        }
        __syncthreads();
        lx = s_lx; ly = s_ly; lz = s_lz;
    }
}

// ---------------------------------------------------------------------------
// Kernel 2: radius ball query. One wave per centroid (4 waves / 256-thread
// block). Scan points in index order 64 at a time; ballot + prefix popcount
// assigns output slots -> lowest indices first, exactly like the reference's
// sort+take-K. Early exit once K neighbors found.
// ---------------------------------------------------------------------------
__global__ __launch_bounds__(256) void ball_kernel(const float* __restrict__ pos,
                                                   const float* __restrict__ cent,
                                                   uint16_t* __restrict__ nb,
                                                   int* __restrict__ cnt_arr,
                                                   float* __restrict__ batch_out) {
    const int wave = threadIdx.x >> 6, lane = threadIdx.x & 63;
    const int c = blockIdx.x * 4 + wave;
    const int b = c >> 11;  // c / kM
    const float R2 = (float)(0.2 * 0.2);  // same double->float rounding as reference

    float cx = cent[(size_t)c * 3 + 0];
    float cy = cent[(size_t)c * 3 + 1];
    float cz = cent[(size_t)c * 3 + 2];
    const float* pb = pos + (size_t)b * kP * 3;

    int cnt = 0;
    for (int p0 = 0; p0 < kP && cnt < kK; p0 += 64) {
        int i = p0 + lane;
        float x = pb[i * 3 + 0], y = pb[i * 3 + 1], z = pb[i * 3 + 2];
        float d2 = dist2(x, y, z, cx, cy, cz);
        bool in = d2 <= R2;
        unsigned long long mask = __ballot(in);
        int rank = __popcll(mask & ((1ull << lane) - 1ull));
        if (in && cnt + rank < kK) {
            nb[(size_t)c * kK + cnt + rank] = (uint16_t)i;
        }
        cnt = min(cnt + (int)__popcll(mask), kK);
    }
    if (lane == 0) {
        cnt_arr[c] = cnt;
        batch_out[c] = (float)b;
    }
}

// ---------------------------------------------------------------------------
// Kernel 3: gather -> MLP (35->64->64->128, ReLU) -> masked max over K.
// One block (256 threads) per centroid. msg/h1/h2 staged in LDS; each thread
// holds its weight column in registers; LDS reads are same-address broadcast.
// ---------------------------------------------------------------------------
__global__ __launch_bounds__(256) void mlp_kernel(const float* __restrict__ pos,
                                                  const float* __restrict__ x,
                                                  const float* __restrict__ cent,
                                                  const uint16_t* __restrict__ nb,
                                                  const int* __restrict__ cnt_arr,
                                                  const float* __restrict__ W1,
                                                  const float* __restrict__ b1,
                                                  const float* __restrict__ W2,
                                                  const float* __restrict__ b2,
                                                  const float* __restrict__ W3,
                                                  const float* __restrict__ b3,
                                                  float* __restrict__ feat_out) {
    const int c = blockIdx.x;
    const int b = c >> 11;
    const int tid = threadIdx.x;

    __shared__ float msg[kK][36];     // 35 used, stride 36
    __shared__ float h1[kK][kH];
    __shared__ float h2[kK][kH];
    __shared__ float s_cent[3];
    __shared__ int s_nb[kK];
    __shared__ int s_cnt;
    __shared__ float red[2][kO];

    if (tid < kK) s_nb[tid] = nb[(size_t)c * kK + tid];
    if (tid == 0) s_cnt = cnt_arr[c];
    if (tid < 3) s_cent[tid] = cent[(size_t)c * 3 + tid];
    __syncthreads();
    const int cnt = s_cnt;

    // gather msg = [x_j (32) | pos_j - cent (3)]
    for (int u = tid; u < kK * 35; u += 256) {
        int k = u / 35, f = u - k * 35;
        float v = 0.0f;
        if (k < cnt) {
            int n = s_nb[k];
            if (f < 32) v = x[((size_t)b * kP + n) * kF + f];
            else        v = pos[((size_t)b * kP + n) * 3 + (f - 32)] - s_cent[f - 32];
        }
        msg[k][f] = v;
    }
    __syncthreads();

    // layer 1: 35 -> 64
    {
        int j = tid & 63, k0 = tid >> 6;  // k0 in [0,4)
        float w[35];
#pragma unroll
        for (int i = 0; i < 35; ++i) w[i] = W1[i * 64 + j];
        float bb = b1[j];
#pragma unroll
        for (int kk = 0; kk < 16; ++kk) {
            int k = k0 * 16 + kk;
            float acc = bb;
#pragma unroll
            for (int i = 0; i < 35; ++i) acc += msg[k][i] * w[i];
            h1[k][j] = fmaxf(acc, 0.0f);
        }
    }
    __syncthreads();

    // layer 2: 64 -> 64
    {
        int j = tid & 63, k0 = tid >> 6;
        float w[64];
#pragma unroll
        for (int i = 0; i < 64; ++i) w[i] = W2[i * 64 + j];
        float bb = b2[j];
#pragma unroll
        for (int kk = 0; kk < 16; ++kk) {
            int k = k0 * 16 + kk;
            float acc = bb;
#pragma unroll
            for (int i = 0; i < 64; ++i) acc += h1[k][i] * w[i];
            h2[k][j] = fmaxf(acc, 0.0f);
        }
    }
    __syncthreads();

    // layer 3: 64 -> 128, fused masked max over valid k
    {
        int j = tid & 127, k0 = tid >> 7;  // k0 in {0,1}
        float w[64];
#pragma unroll
        for (int i = 0; i < 64; ++i) w[i] = W3[i * 128 + j];
        float bb = b3[j];
        float best = -INFINITY;
        for (int kk = 0; kk < 32; ++kk) {
            int k = k0 * 32 + kk;      // wave-uniform bound
            if (k >= cnt) break;
            float acc = bb;
#pragma unroll
            for (int i = 0; i < 64; ++i) acc += h2[k][i] * w[i];
            best = fmaxf(best, fmaxf(acc, 0.0f));
        }
        red[k0][j] = best;
    }
    __syncthreads();

    if (tid < kO) {
        float o = fmaxf(red[0][tid], red[1][tid]);  // cnt>=1 -> red[0] valid
        feat_out[(size_t)c * kO + tid] = o;
    }
}

// ---------------------------------------------------------------------------
extern "C" void kernel_launch(void* const* d_in, const int* in_sizes, int n_in,
                              void* d_out, int out_size, void* d_ws, size_t ws_size,
                              hipStream_t stream) {
    const float* pos = (const float*)d_in[0];
    // d_in[1] = batch (unused; implied by layout)
    const float* x  = (const float*)d_in[2];
    const float* W1 = (const float*)d_in[3];
    const float* b1 = (const float*)d_in[4];
    const float* W2 = (const float*)d_in[5];
    const float* b2 = (const float*)d_in[6];
    const float* W3 = (const float*)d_in[7];
    const float* b3 = (const float*)d_in[8];

    float* out = (float*)d_out;
    float* cent_out  = out;                                   // [B*M, 3]
    float* feat_out  = out + (size_t)kB * kM * 3;             // [B*M, 128]
    float* batch_out = out + (size_t)kB * kM * (3 + kO);      // [B*M]

    char* ws = (char*)d_ws;
    int* cnt_arr   = (int*)ws;                                // B*M ints
    uint16_t* nbuf = (uint16_t*)(ws + (size_t)kB * kM * 4);   // B*M*K u16

    fps_kernel<<<kB, 1024, 0, stream>>>(pos, cent_out);
    ball_kernel<<<(kB * kM) / 4, 256, 0, stream>>>(pos, cent_out, nbuf, cnt_arr, batch_out);
    mlp_kernel<<<kB * kM, 256, 0, stream>>>(pos, x, cent_out, nbuf, cnt_arr,
                                            W1, b1, W2, b2, W3, b3, feat_out);
}

// Round 3
// 3066.463 us; speedup vs baseline: 1.8548x; 1.8548x over previous
//
#include <hip/hip_runtime.h>
#include <stdint.h>
#include <math.h>

// Problem constants (from reference)
constexpr int kB = 8;      // clouds
constexpr int kP = 8192;   // points per cloud
constexpr int kF = 32;     // feature dim
constexpr int kM = 2048;   // centroids per cloud (P * 0.25)
constexpr int kK = 64;     // max neighbors
constexpr int kH = 64;     // hidden dim
constexpr int kO = 128;    // output dim

// Exact-f32 squared distance matching numpy: square elementwise, then
// sequential sum ((dx2+dy2)+dz2). contract(off) forbids fma fusion so this
// matches numpy bit-for-bit regardless of -ffp-contract=fast default.
__device__ __forceinline__ float dist2(float ax, float ay, float az,
                                       float bx, float by, float bz) {
#pragma clang fp contract(off)
    float dx = ax - bx, dy = ay - by, dz = az - bz;
    return (dx * dx + dy * dy) + dz * dz;
}

// ---------------------------------------------------------------------------
// Kernel 1: farthest point sampling. One block (512 threads) per cloud,
// 16 points per thread in registers; pos staged in LDS as SoA for winner
// coordinate lookup (no coords carried through the reduction).
// Argmax key: (float_bits(d) << 32) | ~idx  -> u64 max == max-dist with
// lowest-index tie-break (numpy argmax first-occurrence).
// One barrier per iteration: lane0/wave writes key to ping-pong slots;
// after the barrier all waves redundantly scan the 8 partials (broadcast
// LDS reads) and look up the winner's coords themselves.
// ---------------------------------------------------------------------------
__global__ __launch_bounds__(512) void fps_kernel(const float* __restrict__ pos,
                                                  float* __restrict__ cent_out) {
    const int b = blockIdx.x;
    const int tid = threadIdx.x;
    const float* pb = pos + (size_t)b * kP * 3;

    __shared__ float sxp[kP], syp[kP], szp[kP];   // SoA copy of this cloud
    __shared__ unsigned long long part[2][8];     // ping-pong wave partials

    float px[16], py[16], pz[16], dd[16];
#pragma unroll
    for (int q = 0; q < 16; ++q) {
        int i = tid + q * 512;
        float X = pb[i * 3 + 0];
        float Y = pb[i * 3 + 1];
        float Z = pb[i * 3 + 2];
        px[q] = X; py[q] = Y; pz[q] = Z;
        sxp[i] = X; syp[i] = Y; szp[i] = Z;
        dd[q] = INFINITY;
    }
    __syncthreads();

    // first selected index is 0
    float lx = sxp[0], ly = syp[0], lz = szp[0];
    if (tid == 0) {
        cent_out[(size_t)(b * kM) * 3 + 0] = lx;
        cent_out[(size_t)(b * kM) * 3 + 1] = ly;
        cent_out[(size_t)(b * kM) * 3 + 2] = lz;
    }

    const int wave = tid >> 6, lane = tid & 63;

    for (int m = 1; m < kM; ++m) {
        // update running min-dists; track thread-local best (strict > keeps
        // lowest q == lowest global idx within this thread)
        float bv = -1.0f;
        int bq = 0;
#pragma unroll
        for (int q = 0; q < 16; ++q) {
            float d2 = dist2(px[q], py[q], pz[q], lx, ly, lz);
            float nd = fminf(dd[q], d2);
            dd[q] = nd;
            if (nd > bv) { bv = nd; bq = q; }
        }
        unsigned int bidx = (unsigned int)(tid + bq * 512);
        unsigned long long key =
            ((unsigned long long)__float_as_uint(bv) << 32) | (unsigned int)(~bidx);

        // wave butterfly max (key only: 2 dwords)
#pragma unroll
        for (int off = 32; off >= 1; off >>= 1) {
            unsigned long long ok = __shfl_xor(key, off, 64);
            if (ok > key) key = ok;
        }
        if (lane == 0) part[m & 1][wave] = key;
        __syncthreads();

        // every thread computes the block winner from the 8 partials
        unsigned long long k = part[m & 1][0];
#pragma unroll
        for (int w = 1; w < 8; ++w) {
            unsigned long long o = part[m & 1][w];
            if (o > k) k = o;
        }
        unsigned int wi = ~(unsigned int)k;   // low 32 bits were ~idx
        lx = sxp[wi]; ly = syp[wi]; lz = szp[wi];   // broadcast reads

        if (tid == 0) {
            size_t o = (size_t)(b * kM + m) * 3;
            cent_out[o + 0] = lx;
            cent_out[o + 1] = ly;
            cent_out[o + 2] = lz;
        }
        // no second barrier: next iteration writes the OTHER part[] slot,
        // and the next __syncthreads orders those writes vs these reads.
    }
}

// ---------------------------------------------------------------------------
// Kernel 2: radius ball query. One wave per centroid (4 waves / 256-thread
// block). Scan points in index order 64 at a time; ballot + prefix popcount
// assigns output slots -> lowest indices first, exactly like the reference's
// sort+take-K. Early exit once K neighbors found.
// ---------------------------------------------------------------------------
__global__ __launch_bounds__(256) void ball_kernel(const float* __restrict__ pos,
                                                   const float* __restrict__ cent,
                                                   uint16_t* __restrict__ nb,
                                                   int* __restrict__ cnt_arr,
                                                   float* __restrict__ batch_out) {
    const int wave = threadIdx.x >> 6, lane = threadIdx.x & 63;
    const int c = blockIdx.x * 4 + wave;
    const int b = c >> 11;  // c / kM
    const float R2 = (float)(0.2 * 0.2);  // same double->float rounding as reference

    float cx = cent[(size_t)c * 3 + 0];
    float cy = cent[(size_t)c * 3 + 1];
    float cz = cent[(size_t)c * 3 + 2];
    const float* pb = pos + (size_t)b * kP * 3;

    int cnt = 0;
    for (int p0 = 0; p0 < kP && cnt < kK; p0 += 64) {
        int i = p0 + lane;
        float x = pb[i * 3 + 0], y = pb[i * 3 + 1], z = pb[i * 3 + 2];
        float d2 = dist2(x, y, z, cx, cy, cz);
        bool in = d2 <= R2;
        unsigned long long mask = __ballot(in);
        int rank = __popcll(mask & ((1ull << lane) - 1ull));
        if (in && cnt + rank < kK) {
            nb[(size_t)c * kK + cnt + rank] = (uint16_t)i;
        }
        cnt = min(cnt + (int)__popcll(mask), kK);
    }
    if (lane == 0) {
        cnt_arr[c] = cnt;
        batch_out[c] = (float)b;
    }
}

// ---------------------------------------------------------------------------
// Kernel 3: gather -> MLP (35->64->64->128, ReLU) -> masked max over K.
// One block (256 threads) per centroid. msg/h1/h2 staged in LDS; each thread
// holds its weight column in registers; LDS reads are same-address broadcast.
// ---------------------------------------------------------------------------
__global__ __launch_bounds__(256) void mlp_kernel(const float* __restrict__ pos,
                                                  const float* __restrict__ x,
                                                  const float* __restrict__ cent,
                                                  const uint16_t* __restrict__ nb,
                                                  const int* __restrict__ cnt_arr,
                                                  const float* __restrict__ W1,
                                                  const float* __restrict__ b1,
                                                  const float* __restrict__ W2,
                                                  const float* __restrict__ b2,
                                                  const float* __restrict__ W3,
                                                  const float* __restrict__ b3,
                                                  float* __restrict__ feat_out) {
    const int c = blockIdx.x;
    const int b = c >> 11;
    const int tid = threadIdx.x;

    __shared__ float msg[kK][36];     // 35 used, stride 36
    __shared__ float h1[kK][kH];
    __shared__ float h2[kK][kH];
    __shared__ float s_cent[3];
    __shared__ int s_nb[kK];
    __shared__ int s_cnt;
    __shared__ float red[2][kO];

    if (tid < kK) s_nb[tid] = nb[(size_t)c * kK + tid];
    if (tid == 0) s_cnt = cnt_arr[c];
    if (tid < 3) s_cent[tid] = cent[(size_t)c * 3 + tid];
    __syncthreads();
    const int cnt = s_cnt;

    // gather msg = [x_j (32) | pos_j - cent (3)]
    for (int u = tid; u < kK * 35; u += 256) {
        int k = u / 35, f = u - k * 35;
        float v = 0.0f;
        if (k < cnt) {
            int n = s_nb[k];
            if (f < 32) v = x[((size_t)b * kP + n) * kF + f];
            else        v = pos[((size_t)b * kP + n) * 3 + (f - 32)] - s_cent[f - 32];
        }
        msg[k][f] = v;
    }
    __syncthreads();

    // layer 1: 35 -> 64
    {
        int j = tid & 63, k0 = tid >> 6;  // k0 in [0,4)
        float w[35];
#pragma unroll
        for (int i = 0; i < 35; ++i) w[i] = W1[i * 64 + j];
        float bb = b1[j];
#pragma unroll
        for (int kk = 0; kk < 16; ++kk) {
            int k = k0 * 16 + kk;
            float acc = bb;
#pragma unroll
            for (int i = 0; i < 35; ++i) acc += msg[k][i] * w[i];
            h1[k][j] = fmaxf(acc, 0.0f);
        }
    }
    __syncthreads();

    // layer 2: 64 -> 64
    {
        int j = tid & 63, k0 = tid >> 6;
        float w[64];
#pragma unroll
        for (int i = 0; i < 64; ++i) w[i] = W2[i * 64 + j];
        float bb = b2[j];
#pragma unroll
        for (int kk = 0; kk < 16; ++kk) {
            int k = k0 * 16 + kk;
            float acc = bb;
#pragma unroll
            for (int i = 0; i < 64; ++i) acc += h1[k][i] * w[i];
            h2[k][j] = fmaxf(acc, 0.0f);
        }
    }
    __syncthreads();

    // layer 3: 64 -> 128, fused masked max over valid k
    {
        int j = tid & 127, k0 = tid >> 7;  // k0 in {0,1}
        float w[64];
#pragma unroll
        for (int i = 0; i < 64; ++i) w[i] = W3[i * 128 + j];
        float bb = b3[j];
        float best = -INFINITY;
        for (int kk = 0; kk < 32; ++kk) {
            int k = k0 * 32 + kk;      // wave-uniform bound
            if (k >= cnt) break;
            float acc = bb;
#pragma unroll
            for (int i = 0; i < 64; ++i) acc += h2[k][i] * w[i];
            best = fmaxf(best, fmaxf(acc, 0.0f));
        }
        red[k0][j] = best;
    }
    __syncthreads();

    if (tid < kO) {
        float o = fmaxf(red[0][tid], red[1][tid]);  // cnt>=1 -> red[0] valid
        feat_out[(size_t)c * kO + tid] = o;
    }
}

// ---------------------------------------------------------------------------
extern "C" void kernel_launch(void* const* d_in, const int* in_sizes, int n_in,
                              void* d_out, int out_size, void* d_ws, size_t ws_size,
                              hipStream_t stream) {
    const float* pos = (const float*)d_in[0];
    // d_in[1] = batch (unused; implied by layout)
    const float* x  = (const float*)d_in[2];
    const float* W1 = (const float*)d_in[3];
    const float* b1 = (const float*)d_in[4];
    const float* W2 = (const float*)d_in[5];
    const float* b2 = (const float*)d_in[6];
    const float* W3 = (const float*)d_in[7];
    const float* b3 = (const float*)d_in[8];

    float* out = (float*)d_out;
    float* cent_out  = out;                                   // [B*M, 3]
    float* feat_out  = out + (size_t)kB * kM * 3;             // [B*M, 128]
    float* batch_out = out + (size_t)kB * kM * (3 + kO);      // [B*M]

    char* ws = (char*)d_ws;
    int* cnt_arr   = (int*)ws;                                // B*M ints
    uint16_t* nbuf = (uint16_t*)(ws + (size_t)kB * kM * 4);   // B*M*K u16

    fps_kernel<<<kB, 512, 0, stream>>>(pos, cent_out);
    ball_kernel<<<(kB * kM) / 4, 256, 0, stream>>>(pos, cent_out, nbuf, cnt_arr, batch_out);
    mlp_kernel<<<kB * kM, 256, 0, stream>>>(pos, x, cent_out, nbuf, cnt_arr,
                                            W1, b1, W2, b2, W3, b3, feat_out);
}